// Round 2
// baseline (79.134 us; speedup 1.0000x reference)
//
#include <hip/hip_runtime.h>
#include <hip/hip_bf16.h>

// softConLoss: loss = -mean_{i>=10} log_softmax_c( log(s_c(i)/py_c(i)) )[cls_i]
//   s_c(i) = sum_{j != i, cls_j == c} exp(feat_i . feat_j / 0.1)
// bf16 MFMA Gram tiles; columns permuted+padded so each 32-col tile is
// single-class; exp2 with pre-scaled operand; exact pad/diagonal correction.

constexpr int NROWS = 8192;
constexpr int DIM   = 128;
constexpr int NCLS  = 10;
constexpr int CS    = 16;      // column splits (grid.y of k_main)
constexpr int MMAX  = 8512;    // >= 8192 + 10*31, padded perm rows cap
constexpr float SCALEF = 14.4269504089f; // (1/TEMP) * log2(e)

typedef __attribute__((ext_vector_type(8)))  short  short8;
typedef __attribute__((ext_vector_type(16))) float  f32x16;

struct Meta { int cnt[NCLS]; int segStart[NCLS+1]; int padc[NCLS]; int M; int nTiles; };

// ---- workspace layout (bytes), ~9.6 MB ----
constexpr size_t OFF_FEATB   = 0;                                   // bf16 [NROWS][DIM], scaled
constexpr size_t OFF_FEATA   = OFF_FEATB + (size_t)NROWS * DIM * 2; // bf16 [MMAX][DIM], permuted
constexpr size_t OFF_SLAB    = OFF_FEATA + (size_t)MMAX * DIM * 2;  // f32 [CS][NCLS][NROWS]
constexpr size_t OFF_CLS     = OFF_SLAB + (size_t)CS * NCLS * NROWS * 4;
constexpr size_t OFF_PERM    = OFF_CLS + (size_t)NROWS * 4;
constexpr size_t OFF_TILECLS = OFF_PERM + (size_t)MMAX * 4;
constexpr size_t OFF_META    = OFF_TILECLS + 4 * 512;
constexpr size_t OFF_HIST    = OFF_META + 256;                      // int [256][NCLS]
constexpr size_t OFF_PART    = OFF_HIST + 256 * NCLS * 4;           // f32 [32]
constexpr size_t OFF_CNT     = OFF_PART + 128;                      // int

__device__ inline float exp2a(float x) {
#if __has_builtin(__builtin_amdgcn_exp2f)
  return __builtin_amdgcn_exp2f(x);
#else
  return exp2f(x);
#endif
}

// ---------- kernel 1: class ids + per-chunk(32-row) histograms (64 blocks) ----------
__global__ void k_cls(const float* __restrict__ label, int* __restrict__ cls,
                      int* __restrict__ histg, int* __restrict__ perm,
                      int* __restrict__ counter) {
  __shared__ int hist[4][NCLS];
  const int tid = threadIdx.x;            // 128 threads
  const int blk = blockIdx.x;             // 64 blocks x 128 rows
  if (tid < 4 * NCLS) hist[tid / NCLS][tid % NCLS] = 0;
  if (blk == 0 && tid == 0) *counter = 0; // reset every call (graph replays)
  __syncthreads();
  const int i = blk * 128 + tid;
  int c = 0;
#pragma unroll
  for (int j = 0; j < NCLS; ++j) if (label[i * NCLS + j] > 0.5f) c = j;
  cls[i] = c;
  atomicAdd(&hist[tid >> 5][c], 1);
  for (int p = i; p < MMAX; p += NROWS) perm[p] = -1;   // pads stay -1
  __syncthreads();
  if (tid < 4 * NCLS)
    histg[(blk * 4 + tid / NCLS) * NCLS + tid % NCLS] = hist[tid / NCLS][tid % NCLS];
}

// ---------- kernel 2: prefix + meta + scatter + tile classes (1 block) ----------
__global__ void k_scatter(const int* __restrict__ cls, const int* __restrict__ histg,
                          int* __restrict__ perm, int* __restrict__ tileCls,
                          Meta* __restrict__ meta) {
  __shared__ int hist[256][NCLS];
  __shared__ int gs[16][NCLS];
  __shared__ int ssb[NCLS + 1];
  __shared__ int ctot[NCLS];
  __shared__ int snT;
  const int tid = threadIdx.x;            // 256
#pragma unroll
  for (int c = 0; c < NCLS; ++c) hist[tid][c] = histg[tid * NCLS + c];
  __syncthreads();
  const int tc = tid % NCLS, tg = tid / NCLS;   // 2-level scan: 16 groups of 16
  if (tid < 160) {
    int s = 0;
#pragma unroll
    for (int j = 0; j < 16; ++j) s += hist[tg * 16 + j][tc];
    gs[tg][tc] = s;
  }
  __syncthreads();
  if (tid < NCLS) {
    int run = 0;
#pragma unroll
    for (int g = 0; g < 16; ++g) { int v = gs[g][tid]; gs[g][tid] = run; run += v; }
    ctot[tid] = run;
  }
  __syncthreads();
  if (tid == 0) {
    int s = 0;
    for (int c = 0; c < NCLS; ++c) {
      ssb[c] = s;
      meta->cnt[c] = ctot[c];
      int seg = ((ctot[c] + 31) >> 5) << 5;
      meta->padc[c] = seg - ctot[c];
      s += seg;
    }
    ssb[NCLS] = s;
    meta->M = s; meta->nTiles = s >> 5; snT = s >> 5;
    for (int c = 0; c <= NCLS; ++c) meta->segStart[c] = ssb[c];
  }
  __syncthreads();
  if (tid < 160) {
    int run = gs[tg][tc];
#pragma unroll
    for (int j = 0; j < 16; ++j) { int v = hist[tg * 16 + j][tc]; hist[tg * 16 + j][tc] = run; run += v; }
  }
  __syncthreads();
  // scatter: thread t owns rows [t*32, t*32+32); offsets live in LDS (dynamic idx ok)
  for (int r = 0; r < 32; ++r) {
    int i = tid * 32 + r;
    int c = cls[i];
    int pos = ssb[c] + hist[tid][c];
    hist[tid][c] = hist[tid][c] + 1;
    perm[pos] = i;
  }
  for (int t = tid; t < snT; t += 256) {
    int cc = 0;
    for (int c = 0; c < NCLS; ++c) if (ssb[c] <= t * 32) cc = c;
    tileCls[t] = cc;
  }
}

// ---------- kernel 3: fused bf16 conversions (B scaled, A permuted) ----------
__global__ void k_conv(const float* __restrict__ feat, const int* __restrict__ perm,
                       __hip_bfloat16* __restrict__ featB, __hip_bfloat16* __restrict__ featA) {
  constexpr int NB = NROWS * DIM / 4;
  constexpr int NA = MMAX * DIM / 4;
  int idx = blockIdx.x * 256 + threadIdx.x;
  if (idx < NB) {
    int e = idx * 4;
    float4 v = *(const float4*)(feat + e);
    featB[e + 0] = __float2bfloat16(v.x * SCALEF);
    featB[e + 1] = __float2bfloat16(v.y * SCALEF);
    featB[e + 2] = __float2bfloat16(v.z * SCALEF);
    featB[e + 3] = __float2bfloat16(v.w * SCALEF);
  } else if (idx < NB + NA) {
    int e = (idx - NB) * 4;
    int p = e >> 7, k = e & 127;
    int src = perm[p];
    float4 v = make_float4(0.f, 0.f, 0.f, 0.f);
    if (src >= 0) v = *(const float4*)(feat + (size_t)src * DIM + k);
    featA[e + 0] = __float2bfloat16(v.x);
    featA[e + 1] = __float2bfloat16(v.y);
    featA[e + 2] = __float2bfloat16(v.z);
    featA[e + 3] = __float2bfloat16(v.w);
  }
}

// ---------- kernel 4: main — Gram tiles -> exp2 -> per-class sums ----------
// 256 thr = 4 waves, wave owns 32 output rows. grid (64, CS).
// T14 async-stage: load next tile to regs before compute, ds_write after, 1 barrier/tile.
__global__ __launch_bounds__(256, 4) void k_main(const __hip_bfloat16* __restrict__ featA,
                                                 const __hip_bfloat16* __restrict__ featB,
                                                 const int* __restrict__ tileCls,
                                                 const Meta* __restrict__ meta,
                                                 float* __restrict__ slab) {
  __shared__ __align__(16) char ldsA[2][8192];  // 2 x (32 rows x 256 B), XOR-swizzled
  const int tid  = threadIdx.x;
  const int lane = tid & 63, wid = tid >> 6;
  const int il   = lane & 31, hi = lane >> 5;
  const int i    = blockIdx.x * 128 + wid * 32 + il;
  const int split = blockIdx.y;

  const short8* fb = (const short8*)(featB + (size_t)i * DIM);
  short8 bfrag[8];
#pragma unroll
  for (int kk = 0; kk < 8; ++kk) bfrag[kk] = fb[kk * 2 + hi];

  float acc[NCLS];
#pragma unroll
  for (int c = 0; c < NCLS; ++c) acc[c] = 0.f;

  const int nT = meta->nTiles;

  // this thread's two 16B staging slots (swizzle: byte col ^= (row&15)<<4)
  const int r0 = tid >> 4, s0 = tid & 15;
  const int r1 = r0 + 16;
  const int off0 = r0 * 256 + ((s0 * 16) ^ ((r0 & 15) << 4));
  const int off1 = r1 * 256 + ((s0 * 16) ^ ((r1 & 15) << 4));

  {
    const short8* srcA = (const short8*)(featA + (size_t)split * 32 * DIM);
    *(short8*)(&ldsA[0][off0]) = srcA[r0 * 16 + s0];
    *(short8*)(&ldsA[0][off1]) = srcA[r1 * 16 + s0];
  }
  __syncthreads();

  int cur = 0;
  for (int t = split; t < nT; t += CS) {
    const int tn = t + CS;
    const bool pf = tn < nT;
    short8 v0, v1;
    if (pf) {  // issue next-tile loads early; latency hides under MFMA+exp
      const short8* srcA = (const short8*)(featA + (size_t)tn * 32 * DIM);
      v0 = srcA[r0 * 16 + s0];
      v1 = srcA[r1 * 16 + s0];
    }

    f32x16 Dv;
#pragma unroll
    for (int r = 0; r < 16; ++r) Dv[r] = 0.f;
#pragma unroll
    for (int kk = 0; kk < 8; ++kk) {
      int off = il * 256 + (((kk * 32) + hi * 16) ^ ((il & 15) << 4));
      short8 a = *(const short8*)(&ldsA[cur][off]);
      Dv = __builtin_amdgcn_mfma_f32_32x32x16_bf16(a, bfrag[kk], Dv, 0, 0, 0);
    }

    float ts = 0.f;
#pragma unroll
    for (int r = 0; r < 16; ++r) ts += exp2a(Dv[r]);

    const int ct = tileCls[t];  // wave-uniform switch keeps acc in regs
    switch (ct) {
      case 0: acc[0] += ts; break;  case 1: acc[1] += ts; break;
      case 2: acc[2] += ts; break;  case 3: acc[3] += ts; break;
      case 4: acc[4] += ts; break;  case 5: acc[5] += ts; break;
      case 6: acc[6] += ts; break;  case 7: acc[7] += ts; break;
      case 8: acc[8] += ts; break;  default: acc[9] += ts; break;
    }

    if (pf) {  // write into the OTHER buffer: safe while others still compute on cur
      *(short8*)(&ldsA[cur ^ 1][off0]) = v0;
      *(short8*)(&ldsA[cur ^ 1][off1]) = v1;
    }
    __syncthreads();
    cur ^= 1;
  }

  // combine the two k-half lanes (same output row i)
#pragma unroll
  for (int c = 0; c < NCLS; ++c) acc[c] += __shfl_xor(acc[c], 32, 64);
  if (lane < 32) {  // slab[split][c][i]: coalesced across il
#pragma unroll
    for (int c = 0; c < NCLS; ++c)
      slab[((size_t)split * NCLS + c) * NROWS + i] = acc[c];
  }
}

// ---------- kernel 5: per-row loss + partials + last-block final reduce ----------
__global__ void k_fin(const float* __restrict__ feat, const int* __restrict__ cls,
                      const float* __restrict__ slab, const Meta* __restrict__ meta,
                      float* __restrict__ partials, int* __restrict__ counter,
                      float* __restrict__ out) {
  __shared__ float red[256];
  const int tid = threadIdx.x;
  const int i = blockIdx.x * 256 + tid;
  const int ci = cls[i];
  float s[NCLS];
#pragma unroll
  for (int c = 0; c < NCLS; ++c) s[c] = 0.f;
#pragma unroll
  for (int sp = 0; sp < CS; ++sp) {
#pragma unroll
    for (int c = 0; c < NCLS; ++c) s[c] += slab[((size_t)sp * NCLS + c) * NROWS + i];
  }
#pragma unroll
  for (int c = 0; c < NCLS; ++c) s[c] -= (float)meta->padc[c];  // pads: exp2(0)=1 each
  // diagonal: recompute with identical bf16 roundings
  float sd = 0.f;
  const float* fr = feat + (size_t)i * DIM;
#pragma unroll 8
  for (int k = 0; k < DIM; ++k) {
    float a = __bfloat162float(__float2bfloat16(fr[k]));
    float b = __bfloat162float(__float2bfloat16(fr[k] * SCALEF));
    sd += a * b;
  }
  const float self = exp2a(sd);
  float L[NCLS];
  float mx = -1e30f;
#pragma unroll
  for (int c = 0; c < NCLS; ++c) {
    float sc = s[c] - ((c == ci) ? self : 0.f);
    float py = (float)meta->cnt[c] - ((c == ci) ? 1.f : 0.f);
    L[c] = __logf(sc) - __logf(py);
    mx = fmaxf(mx, L[c]);
  }
  float sum = 0.f, Lt = 0.f;
#pragma unroll
  for (int c = 0; c < NCLS; ++c) {
    sum += __expf(L[c] - mx);
    Lt += (c == ci) ? L[c] : 0.f;
  }
  const float lse = mx + __logf(sum);
  red[tid] = (i >= NCLS) ? (lse - Lt) : 0.f;
  __syncthreads();
  for (int st = 128; st > 0; st >>= 1) {
    if (tid < st) red[tid] += red[tid + st];
    __syncthreads();
  }
  if (tid == 0) {
    partials[blockIdx.x] = red[0];
    __threadfence();
    int old = atomicAdd(counter, 1);
    if (old == (int)gridDim.x - 1) {      // last block: deterministic fixed-order sum
      __threadfence();
      float t = 0.f;
      for (int b = 0; b < (int)gridDim.x; ++b) t += partials[b];
      out[0] = t / (float)(NROWS - NCLS);
    }
  }
}

extern "C" void kernel_launch(void* const* d_in, const int* in_sizes, int n_in,
                              void* d_out, int out_size, void* d_ws, size_t ws_size,
                              hipStream_t stream) {
  const float* label = (const float*)d_in[0];
  const float* feat  = (const float*)d_in[1];
  char* w = (char*)d_ws;
  __hip_bfloat16* featB = (__hip_bfloat16*)(w + OFF_FEATB);
  __hip_bfloat16* featA = (__hip_bfloat16*)(w + OFF_FEATA);
  float* slab    = (float*)(w + OFF_SLAB);
  int*   cls     = (int*)(w + OFF_CLS);
  int*   perm    = (int*)(w + OFF_PERM);
  int*   tileCls = (int*)(w + OFF_TILECLS);
  Meta*  meta    = (Meta*)(w + OFF_META);
  int*   histg   = (int*)(w + OFF_HIST);
  float* part    = (float*)(w + OFF_PART);
  int*   counter = (int*)(w + OFF_CNT);

  k_cls<<<64, 128, 0, stream>>>(label, cls, histg, perm, counter);
  k_scatter<<<1, 256, 0, stream>>>(cls, histg, perm, tileCls, meta);
  k_conv<<<(NROWS * DIM / 4 + MMAX * DIM / 4 + 255) / 256, 256, 0, stream>>>(feat, perm, featB, featA);
  k_main<<<dim3(64, CS), 256, 0, stream>>>(featA, featB, tileCls, meta, slab);
  k_fin<<<NROWS / 256, 256, 0, stream>>>(feat, cls, slab, meta, part, counter, (float*)d_out);
}

// Round 3
// 53.278 us; speedup vs baseline: 1.4853x; 1.4853x over previous
//
#include <hip/hip_runtime.h>
#include <hip/hip_bf16.h>

// softConLoss: loss = -mean_{i>=10} log_softmax_c( log(s_c(i)/py_c(i)) )[cls_i]
//   s_c(i) = sum_{j != i, cls_j == c} exp(feat_i . feat_j / 0.1)
// bf16 MFMA Gram tiles; columns permuted+padded so each 32-col tile is
// single-class; exp2 with pre-scaled operand; exact pad/diagonal correction.

constexpr int NROWS = 8192;
constexpr int DIM   = 128;
constexpr int NCLS  = 10;
constexpr int CS    = 16;      // column splits (grid.y of k_main)
constexpr int MMAX  = 8512;    // >= 8192 + 10*31, padded perm rows cap
constexpr float SCALEF = 14.4269504089f; // (1/TEMP) * log2(e)

typedef __attribute__((ext_vector_type(8)))  short  short8;
typedef __attribute__((ext_vector_type(16))) float  f32x16;

struct Meta { int cnt[NCLS]; int segStart[NCLS+1]; int padc[NCLS]; int M; int nTiles; };

// ---- workspace layout (bytes), ~10 MB ----
constexpr size_t OFF_FEATB   = 0;                                   // bf16 [NROWS][DIM], scaled
constexpr size_t OFF_FEATA   = OFF_FEATB + (size_t)NROWS * DIM * 2; // bf16 [MMAX][DIM], permuted
constexpr size_t OFF_SLAB    = OFF_FEATA + (size_t)MMAX * DIM * 2;  // f32 [CS][NCLS][NROWS]
constexpr size_t OFF_ROWSUM  = OFF_SLAB + (size_t)CS * NCLS * NROWS * 4; // f32 [NCLS][NROWS]
constexpr size_t OFF_DIAG    = OFF_ROWSUM + (size_t)NCLS * NROWS * 4;    // f32 [NROWS]
constexpr size_t OFF_CLS     = OFF_DIAG + (size_t)NROWS * 4;
constexpr size_t OFF_PERM    = OFF_CLS + (size_t)NROWS * 4;
constexpr size_t OFF_TILECLS = OFF_PERM + (size_t)MMAX * 4;
constexpr size_t OFF_META    = OFF_TILECLS + 4 * 512;
constexpr size_t OFF_HIST    = OFF_META + 256;                      // int [256][NCLS]
constexpr size_t OFF_PART    = OFF_HIST + 256 * NCLS * 4;           // f32 [32]
constexpr size_t OFF_CNT     = OFF_PART + 128;                      // int

__device__ inline float exp2a(float x) {
#if __has_builtin(__builtin_amdgcn_exp2f)
  return __builtin_amdgcn_exp2f(x);
#else
  return exp2f(x);
#endif
}

// ---------- kernel 1: class ids + per-chunk(32-row) histograms (64 blocks) ----------
__global__ void k_cls(const float* __restrict__ label, int* __restrict__ cls,
                      int* __restrict__ histg, int* __restrict__ perm,
                      int* __restrict__ counter) {
  __shared__ int hist[4][NCLS];
  const int tid = threadIdx.x;            // 128 threads
  const int blk = blockIdx.x;             // 64 blocks x 128 rows
  if (tid < 4 * NCLS) hist[tid / NCLS][tid % NCLS] = 0;
  if (blk == 0 && tid == 0) *counter = 0; // reset every call (graph replays)
  __syncthreads();
  const int i = blk * 128 + tid;
  int c = 0;
#pragma unroll
  for (int j = 0; j < NCLS; ++j) if (label[i * NCLS + j] > 0.5f) c = j;
  cls[i] = c;
  atomicAdd(&hist[tid >> 5][c], 1);
  for (int p = i; p < MMAX; p += NROWS) perm[p] = -1;   // pads stay -1
  __syncthreads();
  if (tid < 4 * NCLS)
    histg[(blk * 4 + tid / NCLS) * NCLS + tid % NCLS] = hist[tid / NCLS][tid % NCLS];
}

// ---------- kernel 2: prefix + meta + scatter + tile classes (1 block) ----------
__global__ void k_scatter(const int* __restrict__ cls, const int* __restrict__ histg,
                          int* __restrict__ perm, int* __restrict__ tileCls,
                          Meta* __restrict__ meta) {
  __shared__ int hist[256][NCLS];
  __shared__ int lcls[NROWS];             // 32 KB: cls staged coalesced
  __shared__ int gs[16][NCLS];
  __shared__ int ssb[NCLS + 1];
  __shared__ int ctot[NCLS];
  __shared__ int snT;
  const int tid = threadIdx.x;            // 256
#pragma unroll
  for (int c = 0; c < NCLS; ++c) hist[tid][c] = histg[tid * NCLS + c];
  for (int j = tid; j < NROWS; j += 256) lcls[j] = cls[j];
  __syncthreads();
  const int tc = tid % NCLS, tg = tid / NCLS;   // 2-level scan: 16 groups of 16
  if (tid < 160) {
    int s = 0;
#pragma unroll
    for (int j = 0; j < 16; ++j) s += hist[tg * 16 + j][tc];
    gs[tg][tc] = s;
  }
  __syncthreads();
  if (tid < NCLS) {
    int run = 0;
#pragma unroll
    for (int g = 0; g < 16; ++g) { int v = gs[g][tid]; gs[g][tid] = run; run += v; }
    ctot[tid] = run;
  }
  __syncthreads();
  if (tid == 0) {
    int s = 0;
    for (int c = 0; c < NCLS; ++c) {
      ssb[c] = s;
      meta->cnt[c] = ctot[c];
      int seg = ((ctot[c] + 31) >> 5) << 5;
      meta->padc[c] = seg - ctot[c];
      s += seg;
    }
    ssb[NCLS] = s;
    meta->M = s; meta->nTiles = s >> 5; snT = s >> 5;
    for (int c = 0; c <= NCLS; ++c) meta->segStart[c] = ssb[c];
  }
  __syncthreads();
  if (tid < 160) {
    int run = gs[tg][tc];
#pragma unroll
    for (int j = 0; j < 16; ++j) { int v = hist[tg * 16 + j][tc]; hist[tg * 16 + j][tc] = run; run += v; }
  }
  __syncthreads();
  // scatter: thread t owns rows [t*32, t*32+32); offsets + cls live in LDS
  for (int r = 0; r < 32; ++r) {
    int i = tid * 32 + r;
    int c = lcls[i];
    int pos = ssb[c] + hist[tid][c];
    hist[tid][c] = hist[tid][c] + 1;
    perm[pos] = i;
  }
  for (int t = tid; t < snT; t += 256) {
    int cc = 0;
    for (int c = 0; c < NCLS; ++c) if (ssb[c] <= t * 32) cc = c;
    tileCls[t] = cc;
  }
}

// ---------- kernel 3: fused bf16 conversions + diagonal ----------
// B branch: 32 consecutive threads own one row -> shfl-reduce the self-dot.
__global__ void k_conv(const float* __restrict__ feat, const int* __restrict__ perm,
                       __hip_bfloat16* __restrict__ featB, __hip_bfloat16* __restrict__ featA,
                       float* __restrict__ diag) {
  constexpr int NB = NROWS * DIM / 4;   // 65536 threads (256 blocks), 32-aligned groups
  constexpr int NA = MMAX * DIM / 4;
  int idx = blockIdx.x * 256 + threadIdx.x;
  if (idx < NB) {
    int e = idx * 4;
    float4 v = *(const float4*)(feat + e);
    float a0 = __bfloat162float(__float2bfloat16(v.x));
    float a1 = __bfloat162float(__float2bfloat16(v.y));
    float a2 = __bfloat162float(__float2bfloat16(v.z));
    float a3 = __bfloat162float(__float2bfloat16(v.w));
    __hip_bfloat16 b0 = __float2bfloat16(v.x * SCALEF);
    __hip_bfloat16 b1 = __float2bfloat16(v.y * SCALEF);
    __hip_bfloat16 b2 = __float2bfloat16(v.z * SCALEF);
    __hip_bfloat16 b3 = __float2bfloat16(v.w * SCALEF);
    featB[e + 0] = b0; featB[e + 1] = b1; featB[e + 2] = b2; featB[e + 3] = b3;
    float sd = a0 * __bfloat162float(b0) + a1 * __bfloat162float(b1)
             + a2 * __bfloat162float(b2) + a3 * __bfloat162float(b3);
#pragma unroll
    for (int st = 1; st < 32; st <<= 1) sd += __shfl_xor(sd, st, 64);
    if ((e & 127) == 0) diag[e >> 7] = exp2a(sd);
  } else if (idx < NB + NA) {
    int e = (idx - NB) * 4;
    int p = e >> 7, k = e & 127;
    int src = perm[p];
    float4 v = make_float4(0.f, 0.f, 0.f, 0.f);
    if (src >= 0) v = *(const float4*)(feat + (size_t)src * DIM + k);
    featA[e + 0] = __float2bfloat16(v.x);
    featA[e + 1] = __float2bfloat16(v.y);
    featA[e + 2] = __float2bfloat16(v.z);
    featA[e + 3] = __float2bfloat16(v.w);
  }
}

// ---------- kernel 4: main — Gram tiles -> exp2 -> per-class sums ----------
// 256 thr = 4 waves, wave owns 32 output rows. grid (64, CS).
// T14 async-stage: load next tile to regs before compute, ds_write after, 1 barrier/tile.
__global__ __launch_bounds__(256, 4) void k_main(const __hip_bfloat16* __restrict__ featA,
                                                 const __hip_bfloat16* __restrict__ featB,
                                                 const int* __restrict__ tileCls,
                                                 const Meta* __restrict__ meta,
                                                 float* __restrict__ slab) {
  __shared__ __align__(16) char ldsA[2][8192];  // 2 x (32 rows x 256 B), XOR-swizzled
  const int tid  = threadIdx.x;
  const int lane = tid & 63, wid = tid >> 6;
  const int il   = lane & 31, hi = lane >> 5;
  const int i    = blockIdx.x * 128 + wid * 32 + il;
  const int split = blockIdx.y;

  const short8* fb = (const short8*)(featB + (size_t)i * DIM);
  short8 bfrag[8];
#pragma unroll
  for (int kk = 0; kk < 8; ++kk) bfrag[kk] = fb[kk * 2 + hi];

  float acc[NCLS];
#pragma unroll
  for (int c = 0; c < NCLS; ++c) acc[c] = 0.f;

  const int nT = meta->nTiles;

  // this thread's two 16B staging slots (swizzle: byte col ^= (row&15)<<4)
  const int r0 = tid >> 4, s0 = tid & 15;
  const int r1 = r0 + 16;
  const int off0 = r0 * 256 + ((s0 * 16) ^ ((r0 & 15) << 4));
  const int off1 = r1 * 256 + ((s0 * 16) ^ ((r1 & 15) << 4));

  {
    const short8* srcA = (const short8*)(featA + (size_t)split * 32 * DIM);
    *(short8*)(&ldsA[0][off0]) = srcA[r0 * 16 + s0];
    *(short8*)(&ldsA[0][off1]) = srcA[r1 * 16 + s0];
  }
  __syncthreads();

  int cur = 0;
  for (int t = split; t < nT; t += CS) {
    const int tn = t + CS;
    const bool pf = tn < nT;
    short8 v0, v1;
    if (pf) {  // issue next-tile loads early; latency hides under MFMA+exp
      const short8* srcA = (const short8*)(featA + (size_t)tn * 32 * DIM);
      v0 = srcA[r0 * 16 + s0];
      v1 = srcA[r1 * 16 + s0];
    }

    f32x16 Dv;
#pragma unroll
    for (int r = 0; r < 16; ++r) Dv[r] = 0.f;
#pragma unroll
    for (int kk = 0; kk < 8; ++kk) {
      int off = il * 256 + (((kk * 32) + hi * 16) ^ ((il & 15) << 4));
      short8 a = *(const short8*)(&ldsA[cur][off]);
      Dv = __builtin_amdgcn_mfma_f32_32x32x16_bf16(a, bfrag[kk], Dv, 0, 0, 0);
    }

    // exp2 + pairwise tree sum (cuts 16-deep dependent fadd chain)
    float e0[8];
#pragma unroll
    for (int r = 0; r < 8; ++r) e0[r] = exp2a(Dv[2 * r]) + exp2a(Dv[2 * r + 1]);
    float e1 = (e0[0] + e0[1]) + (e0[2] + e0[3]);
    float e2 = (e0[4] + e0[5]) + (e0[6] + e0[7]);
    float ts = e1 + e2;

    const int ct = tileCls[t];  // wave-uniform switch keeps acc in regs
    switch (ct) {
      case 0: acc[0] += ts; break;  case 1: acc[1] += ts; break;
      case 2: acc[2] += ts; break;  case 3: acc[3] += ts; break;
      case 4: acc[4] += ts; break;  case 5: acc[5] += ts; break;
      case 6: acc[6] += ts; break;  case 7: acc[7] += ts; break;
      case 8: acc[8] += ts; break;  default: acc[9] += ts; break;
    }

    if (pf) {  // write into the OTHER buffer: safe while others still compute on cur
      *(short8*)(&ldsA[cur ^ 1][off0]) = v0;
      *(short8*)(&ldsA[cur ^ 1][off1]) = v1;
    }
    __syncthreads();
    cur ^= 1;
  }

  // combine the two k-half lanes (same output row i)
#pragma unroll
  for (int c = 0; c < NCLS; ++c) acc[c] += __shfl_xor(acc[c], 32, 64);
  if (lane < 32) {  // slab[split][c][i]: coalesced across il
#pragma unroll
    for (int c = 0; c < NCLS; ++c)
      slab[((size_t)split * NCLS + c) * NROWS + i] = acc[c];
  }
}

// ---------- kernel 5: reduce slab over splits (coalesced, wide grid) ----------
__global__ void k_sumslab(const float* __restrict__ slab, const Meta* __restrict__ meta,
                          float* __restrict__ rowsum) {
  const int idx = blockIdx.x * 256 + threadIdx.x;   // 320 blocks: idx in [0, NCLS*NROWS)
  const int c = idx >> 13;                           // idx / NROWS
  float s = 0.f;
#pragma unroll
  for (int sp = 0; sp < CS; ++sp) s += slab[(size_t)sp * NCLS * NROWS + idx];
  rowsum[idx] = s - (float)meta->padc[c];            // pads contributed exp2(0)=1 each
}

// ---------- kernel 6: per-row loss + partials + last-block final reduce ----------
__global__ void k_fin(const float* __restrict__ rowsum, const float* __restrict__ diag,
                      const int* __restrict__ cls, const Meta* __restrict__ meta,
                      float* __restrict__ partials, int* __restrict__ counter,
                      float* __restrict__ out) {
  __shared__ float red[256];
  const int tid = threadIdx.x;
  const int i = blockIdx.x * 256 + tid;
  const int ci = cls[i];
  const float self = diag[i];
  float L[NCLS];
  float mx = -1e30f;
#pragma unroll
  for (int c = 0; c < NCLS; ++c) {
    float sc = rowsum[c * NROWS + i] - ((c == ci) ? self : 0.f);
    float py = (float)meta->cnt[c] - ((c == ci) ? 1.f : 0.f);
    L[c] = __logf(sc) - __logf(py);
    mx = fmaxf(mx, L[c]);
  }
  float sum = 0.f, Lt = 0.f;
#pragma unroll
  for (int c = 0; c < NCLS; ++c) {
    sum += __expf(L[c] - mx);
    Lt += (c == ci) ? L[c] : 0.f;
  }
  const float lse = mx + __logf(sum);
  red[tid] = (i >= NCLS) ? (lse - Lt) : 0.f;
  __syncthreads();
  for (int st = 128; st > 0; st >>= 1) {
    if (tid < st) red[tid] += red[tid + st];
    __syncthreads();
  }
  if (tid == 0) {
    partials[blockIdx.x] = red[0];
    __threadfence();
    int old = atomicAdd(counter, 1);
    if (old == (int)gridDim.x - 1) {      // last block: deterministic fixed-order sum
      __threadfence();
      float t = 0.f;
      for (int b = 0; b < (int)gridDim.x; ++b) t += partials[b];
      out[0] = t / (float)(NROWS - NCLS);
    }
  }
}

extern "C" void kernel_launch(void* const* d_in, const int* in_sizes, int n_in,
                              void* d_out, int out_size, void* d_ws, size_t ws_size,
                              hipStream_t stream) {
  const float* label = (const float*)d_in[0];
  const float* feat  = (const float*)d_in[1];
  char* w = (char*)d_ws;
  __hip_bfloat16* featB = (__hip_bfloat16*)(w + OFF_FEATB);
  __hip_bfloat16* featA = (__hip_bfloat16*)(w + OFF_FEATA);
  float* slab    = (float*)(w + OFF_SLAB);
  float* rowsum  = (float*)(w + OFF_ROWSUM);
  float* diag    = (float*)(w + OFF_DIAG);
  int*   cls     = (int*)(w + OFF_CLS);
  int*   perm    = (int*)(w + OFF_PERM);
  int*   tileCls = (int*)(w + OFF_TILECLS);
  Meta*  meta    = (Meta*)(w + OFF_META);
  int*   histg   = (int*)(w + OFF_HIST);
  float* part    = (float*)(w + OFF_PART);
  int*   counter = (int*)(w + OFF_CNT);

  k_cls<<<64, 128, 0, stream>>>(label, cls, histg, perm, counter);
  k_scatter<<<1, 256, 0, stream>>>(cls, histg, perm, tileCls, meta);
  k_conv<<<(NROWS * DIM / 4 + MMAX * DIM / 4) / 256, 256, 0, stream>>>(feat, perm, featB, featA, diag);
  k_main<<<dim3(64, CS), 256, 0, stream>>>(featA, featB, tileCls, meta, slab);
  k_sumslab<<<NCLS * NROWS / 256, 256, 0, stream>>>(slab, meta, rowsum);
  k_fin<<<NROWS / 256, 256, 0, stream>>>(rowsum, diag, cls, meta, part, counter, (float*)d_out);
}